// Round 1
// baseline (2920.087 us; speedup 1.0000x reference)
//
#include <hip/hip_runtime.h>

// Decoder: h0 = latent@fc_W^T + fc_b ; 128-step LSTM with folded feedback ;
// Y = H_hist @ out_W^T + out_b.
// All bf16 matrices in ws are stored "swz" : element (row,k) at k ^ ((row&7)<<3)
// (XOR on k bits 3..5, block-preserving within 64-col chunks) so that
// global_load_lds (linear LDS dest) + swizzled ds_read_b128 is bank-conflict-free.

typedef __attribute__((ext_vector_type(8))) short bfrag;   // 8 x bf16
typedef __attribute__((ext_vector_type(4))) float f32x4;

#define MFMA(a,b,c) __builtin_amdgcn_mfma_f32_16x16x32_bf16(a,b,c,0,0,0)

__device__ __forceinline__ short f2bf(float x){
  unsigned u = __builtin_bit_cast(unsigned, x);
  u = (u + 0x7fffu + ((u >> 16) & 1u)) >> 16;
  return (short)u;
}
__device__ __forceinline__ float bf2f(short h){
  unsigned u = ((unsigned)(unsigned short)h) << 16;
  return __builtin_bit_cast(float, u);
}

__device__ __forceinline__ void gll16(const void* g, void* l){
  __builtin_amdgcn_global_load_lds((const __attribute__((address_space(1))) void*)g,
                                   (__attribute__((address_space(3))) void*)l, 16, 0, 0);
}

// stage a 64x64 bf16 tile (pre-swizzled global, row-major ld=ldk) into LDS (linear image).
// 8 x 1KB instructions; wave wv issues j = 2wv, 2wv+1. lane l of instr j covers
// row j*8 + (l>>3), 16 bytes at col (l&7)*8.
__device__ __forceinline__ void stage_t(const short* gRC, int ldk, short* lds, int lane, int wv){
#pragma unroll
  for (int jj = 0; jj < 2; ++jj){
    int j = wv*2 + jj;
    const short* src = gRC + (size_t)(j*8 + (lane>>3))*ldk + ((lane&7)*8);
    gll16(src, lds + j*512);
  }
}

// read an MFMA fragment (16x16x32 bf16): lane&15 -> row (non-K), (lane>>4)*8 -> k group.
// LDS tile is the swizzled image: elem = row*64 + (k ^ ((row&7)<<3)).
__device__ __forceinline__ bfrag frag(const short* t, int r, int kk, int lane){
  int row = r + (lane & 15);
  int k0  = (kk<<5) + ((lane>>4)<<3);
  return *(const bfrag*)(t + row*64 + (k0 ^ ((row & 7)<<3)));
}

// generic 64x64-tile GEMM core over 3 K-segments {(0,0),(S,0),(0,S)}, CPS chunks each.
template<int CPS>
__device__ __forceinline__ void core_seg3(const short* Ag, int ldA, const short* Bg, int ldB, int S,
                                          short* As, short* Bs, f32x4 (&acc)[2][2],
                                          int lane, int wv, int wr, int wc){
  int ao = 0, bo = 0;
  stage_t(Ag, ldA, As, lane, wv);
  stage_t(Bg, ldB, Bs, lane, wv);
  __syncthreads();
  int buf = 0;
  const int NCH = 3*CPS;
  for (int c = 0; c < NCH; ++c){
    if (c+1 < NCH){
      int cn = c+1, seg = cn/CPS, kc = cn - seg*CPS;
      ao = kc*64 + (seg==1 ? S : 0);
      bo = kc*64 + (seg==2 ? S : 0);
      stage_t(Ag+ao, ldA, As+(buf^1)*4096, lane, wv);
      stage_t(Bg+bo, ldB, Bs+(buf^1)*4096, lane, wv);
    }
    const short* At = As + buf*4096;
    const short* Bt = Bs + buf*4096;
#pragma unroll
    for (int kk = 0; kk < 2; ++kk){
      bfrag a0 = frag(At, wr,    kk, lane), a1 = frag(At, wr+16, kk, lane);
      bfrag b0 = frag(Bt, wc,    kk, lane), b1 = frag(Bt, wc+16, kk, lane);
      acc[0][0] = MFMA(a0,b0,acc[0][0]); acc[0][1] = MFMA(a0,b1,acc[0][1]);
      acc[1][0] = MFMA(a1,b0,acc[1][0]); acc[1][1] = MFMA(a1,b1,acc[1][1]);
    }
    __syncthreads();
    buf ^= 1;
  }
}

// ---------------- setup kernels ----------------

// elementwise splits (hi/lo bf16) into swizzled layouts + permuted bias0
__global__ void k_prep(const float* __restrict__ W_ih, const float* __restrict__ out_W,
                       const float* __restrict__ latent, const float* __restrict__ fc_W,
                       const float* __restrict__ b_ih, const float* __restrict__ b_hh,
                       short* __restrict__ WihE, short* __restrict__ owTE,
                       short* __restrict__ latE, short* __restrict__ fcwE,
                       short* __restrict__ owB, float* __restrict__ bias0){
  int T = blockDim.x*gridDim.x, t0 = blockIdx.x*blockDim.x + threadIdx.x;
  for (int idx = t0; idx < 4096*256; idx += T){           // W_ih -> [4096][256|256]
    int r = idx >> 8, j = idx & 255;
    float v = W_ih[idx];
    short hi = f2bf(v); short lo = f2bf(v - bf2f(hi));
    int sc = (r&7)<<3;
    WihE[(size_t)r*512 + (j^sc)]        = hi;
    WihE[(size_t)r*512 + ((256+j)^sc)]  = lo;
  }
  for (int idx = t0; idx < 1024*256; idx += T){           // out_W^T -> [1024][256|256]
    int k = idx >> 8, j = idx & 255;
    float v = out_W[(size_t)j*1024 + k];
    short hi = f2bf(v); short lo = f2bf(v - bf2f(hi));
    int sc = (k&7)<<3;
    owTE[(size_t)k*512 + (j^sc)]        = hi;
    owTE[(size_t)k*512 + ((256+j)^sc)]  = lo;
  }
  for (int idx = t0; idx < 256*1024; idx += T){           // out_W -> bf16 [256][1024]
    int o = idx >> 10, k = idx & 1023;
    int sc = (o&7)<<3;
    owB[(size_t)o*1024 + (k^sc)] = f2bf(out_W[idx]);
  }
  for (int idx = t0; idx < 256*512; idx += T){            // latent -> [256][512|512]
    int b = idx >> 9, j = idx & 511;
    float v = latent[idx];
    short hi = f2bf(v); short lo = f2bf(v - bf2f(hi));
    int sc = (b&7)<<3;
    latE[(size_t)b*1024 + (j^sc)]       = hi;
    latE[(size_t)b*1024 + ((512+j)^sc)] = lo;
  }
  for (int idx = t0; idx < 1024*512; idx += T){           // fc_W -> [1024][512|512]
    int n = idx >> 9, j = idx & 511;
    float v = fc_W[idx];
    short hi = f2bf(v); short lo = f2bf(v - bf2f(hi));
    int sc = (n&7)<<3;
    fcwE[(size_t)n*1024 + (j^sc)]       = hi;
    fcwE[(size_t)n*1024 + ((512+j)^sc)] = lo;
  }
  for (int r = t0; r < 4096; r += T){                     // bias0 permuted (u*4+g)
    int rp = ((r & 1023)<<2) | (r >> 10);
    bias0[rp] = b_ih[r] + b_hh[r];
  }
}

__global__ void k_bias1(const float* __restrict__ W_ih, const float* __restrict__ out_b,
                        const float* __restrict__ bias0, float* __restrict__ bias1){
  int r = blockIdx.x*256 + threadIdx.x;            // 4096 threads
  float s = 0.f;
  for (int j = 0; j < 256; ++j) s += W_ih[(size_t)r*256 + j]*out_b[j];
  int rp = ((r & 1023)<<2) | (r >> 10);
  bias1[rp] = bias0[rp] + s;
}

// W_total = W_hh + W_ih@out_W (split-bf16, 3-term) ; write bf16(Wt), bf16(W_hh), rows permuted
__global__ __launch_bounds__(256) void k_wtotal(const short* __restrict__ WihE, const short* __restrict__ owTE,
                                                const float* __restrict__ W_hh,
                                                short* __restrict__ Wt, short* __restrict__ W0){
  __shared__ __align__(16) short As[2*4096];
  __shared__ __align__(16) short Bs[2*4096];
  int tid = threadIdx.x, lane = tid & 63, wv = tid >> 6;
  int wr = (wv>>1)*32, wc = (wv&1)*32;
  int Rm = blockIdx.x*64, Rn = blockIdx.y*64;
  f32x4 acc[2][2] = {};
  core_seg3<4>(WihE + (size_t)Rm*512, 512, owTE + (size_t)Rn*512, 512, 256,
               As, Bs, acc, lane, wv, wr, wc);
#pragma unroll
  for (int mi = 0; mi < 2; ++mi)
#pragma unroll
  for (int ni = 0; ni < 2; ++ni)
#pragma unroll
  for (int r = 0; r < 4; ++r){
    int row = Rm + wr + mi*16 + ((lane>>4)<<2) + r;   // original gate row
    int col = Rn + wc + ni*16 + (lane & 15);          // k
    float whh = W_hh[(size_t)row*1024 + col];
    int rp = ((row & 1023)<<2) | (row >> 10);
    int cs = col ^ ((rp&7)<<3);
    Wt[(size_t)rp*1024 + cs] = f2bf(acc[mi][ni][r] + whh);
    W0[(size_t)rp*1024 + cs] = f2bf(whh);
  }
}

// h0 = latent@fc_W^T + fc_b (split-bf16 3-term); writes A0 (hi|lo) and zeroes c
__global__ __launch_bounds__(256) void k_h0(const short* __restrict__ latE, const short* __restrict__ fcwE,
                                            const float* __restrict__ fc_b,
                                            short* __restrict__ A0, float* __restrict__ Cst){
  __shared__ __align__(16) short As[2*4096];
  __shared__ __align__(16) short Bs[2*4096];
  int tid = threadIdx.x, lane = tid & 63, wv = tid >> 6;
  int wr = (wv>>1)*32, wc = (wv&1)*32;
  int Rm = blockIdx.x*64, Rn = blockIdx.y*64;
  f32x4 acc[2][2] = {};
  core_seg3<8>(latE + (size_t)Rm*1024, 1024, fcwE + (size_t)Rn*1024, 1024, 512,
               As, Bs, acc, lane, wv, wr, wc);
#pragma unroll
  for (int mi = 0; mi < 2; ++mi)
#pragma unroll
  for (int ni = 0; ni < 2; ++ni)
#pragma unroll
  for (int r = 0; r < 4; ++r){
    int row = Rm + wr + mi*16 + ((lane>>4)<<2) + r;   // batch
    int col = Rn + wc + ni*16 + (lane & 15);          // unit
    float h = acc[mi][ni][r] + fc_b[col];
    short hi = f2bf(h); short lo = f2bf(h - bf2f(hi));
    int sc = (row&7)<<3;
    A0[(size_t)row*2048 + (col^sc)]          = hi;
    A0[(size_t)row*2048 + ((1024+col)^sc)]   = lo;
    Cst[(size_t)row*1024 + col] = 0.f;
  }
}

// ---------------- the recurrent step ----------------
// gates(64x64 tile) = [h_hi|h_lo] @ Bw^T + bias ; fused LSTM cell for 16 units x 64 rows.
__global__ __launch_bounds__(256) void k_step(const short* __restrict__ A, const short* __restrict__ Bw,
                                              const float* __restrict__ bias, float* __restrict__ Cst,
                                              short* __restrict__ Anext, short* __restrict__ Ht){
  __shared__ __align__(16) short Hs[2*4096];
  __shared__ __align__(16) short Ls[2*4096];
  __shared__ __align__(16) short Bs[2*4096];
  __shared__ __align__(16) float Lacc[64*68];
  int tid = threadIdx.x, lane = tid & 63, wv = tid >> 6;
  int wr = (wv>>1)*32, wc = (wv&1)*32;
  int Rm = blockIdx.x*64;                 // batch block
  int Rn = blockIdx.y*64;                 // permuted gate block (16 units)
  const short* Ab = A  + (size_t)Rm*2048;
  const short* Bb = Bw + (size_t)Rn*1024;
  f32x4 acc[2][2] = {};
  stage_t(Ab,        2048, Hs, lane, wv);
  stage_t(Ab + 1024, 2048, Ls, lane, wv);
  stage_t(Bb,        1024, Bs, lane, wv);
  __syncthreads();
  int buf = 0;
  for (int c = 0; c < 16; ++c){
    if (c+1 < 16){
      int k = (c+1)*64;
      stage_t(Ab + k,        2048, Hs + (buf^1)*4096, lane, wv);
      stage_t(Ab + 1024 + k, 2048, Ls + (buf^1)*4096, lane, wv);
      stage_t(Bb + k,        1024, Bs + (buf^1)*4096, lane, wv);
    }
    const short* Htile = Hs + buf*4096;
    const short* Ltile = Ls + buf*4096;
    const short* Btile = Bs + buf*4096;
#pragma unroll
    for (int kk = 0; kk < 2; ++kk){
      bfrag b0 = frag(Btile, wc,    kk, lane), b1 = frag(Btile, wc+16, kk, lane);
      bfrag h0 = frag(Htile, wr,    kk, lane), h1 = frag(Htile, wr+16, kk, lane);
      bfrag l0 = frag(Ltile, wr,    kk, lane), l1 = frag(Ltile, wr+16, kk, lane);
      acc[0][0] = MFMA(h0,b0,acc[0][0]); acc[0][1] = MFMA(h0,b1,acc[0][1]);
      acc[1][0] = MFMA(h1,b0,acc[1][0]); acc[1][1] = MFMA(h1,b1,acc[1][1]);
      acc[0][0] = MFMA(l0,b0,acc[0][0]); acc[0][1] = MFMA(l0,b1,acc[0][1]);
      acc[1][0] = MFMA(l1,b0,acc[1][0]); acc[1][1] = MFMA(l1,b1,acc[1][1]);
    }
    __syncthreads();
    buf ^= 1;
  }
  // gates + bias -> LDS
#pragma unroll
  for (int ni = 0; ni < 2; ++ni){
    int col = wc + ni*16 + (lane & 15);
    float bv = bias[Rn + col];
#pragma unroll
    for (int mi = 0; mi < 2; ++mi)
#pragma unroll
    for (int r = 0; r < 4; ++r){
      int row = wr + mi*16 + ((lane>>4)<<2) + r;
      Lacc[row*68 + col] = acc[mi][ni][r] + bv;
    }
  }
  __syncthreads();
  // LSTM cell: 64 rows x 16 units, 4 cells/thread
#pragma unroll
  for (int i = 0; i < 4; ++i){
    int cell = i*256 + tid;
    int m = cell >> 4, u = cell & 15;
    float4 g4 = *(const float4*)&Lacc[m*68 + u*4];
    float I = 1.f/(1.f + __expf(-g4.x));
    float F = 1.f/(1.f + __expf(-g4.y));
    float G = tanhf(g4.z);
    float O = 1.f/(1.f + __expf(-g4.w));
    int gm = Rm + m, gu = (Rn>>2) + u;
    float co = Cst[(size_t)gm*1024 + gu];
    float cn = F*co + I*G;
    float hn = O*tanhf(cn);
    Cst[(size_t)gm*1024 + gu] = cn;
    short hi = f2bf(hn); short lo = f2bf(hn - bf2f(hi));
    int sc = (gm&7)<<3;
    Anext[(size_t)gm*2048 + (gu^sc)]        = hi;
    Anext[(size_t)gm*2048 + ((1024+gu)^sc)] = lo;
    Ht[(size_t)gm*1024 + (gu^sc)]           = hi;
  }
}

// ---------------- final Y GEMM ----------------
// out[b][t][o] = H[t*256+b] . owB[o] + out_b[o] ; tile 128x256, 8 waves.
__global__ __launch_bounds__(512) void k_y(const short* __restrict__ Hh, const short* __restrict__ owB,
                                           const float* __restrict__ out_b, float* __restrict__ out){
  __shared__ __align__(16) short As[2*8192];    // [128][64] x2
  __shared__ __align__(16) short Bs[2*16384];   // [256][64] x2
  int tid = threadIdx.x, lane = tid & 63, wv = tid >> 6;  // 8 waves
  int wr = (wv>>2)*64, wc = (wv&3)*64;
  size_t Rm = (size_t)blockIdx.x * 128;
  const short* Ab = Hh + Rm*1024;
  f32x4 acc[4][4] = {};
  auto stA = [&](int c, short* dst){
#pragma unroll
    for (int jj = 0; jj < 2; ++jj){ int j = wv*2 + jj;
      gll16(Ab + (size_t)(j*8 + (lane>>3))*1024 + c*64 + (lane&7)*8, dst + j*512); }
  };
  auto stB = [&](int c, short* dst){
#pragma unroll
    for (int jj = 0; jj < 4; ++jj){ int j = wv*4 + jj;
      gll16(owB + (size_t)(j*8 + (lane>>3))*1024 + c*64 + (lane&7)*8, dst + j*512); }
  };
  stA(0, As); stB(0, Bs);
  __syncthreads();
  int buf = 0;
  for (int c = 0; c < 16; ++c){
    if (c+1 < 16){ stA(c+1, As + (buf^1)*8192); stB(c+1, Bs + (buf^1)*16384); }
    const short* At = As + buf*8192;
    const short* Bt = Bs + buf*16384;
#pragma unroll
    for (int kk = 0; kk < 2; ++kk){
      bfrag av[4], bv[4];
#pragma unroll
      for (int mi = 0; mi < 4; ++mi) av[mi] = frag(At, wr + mi*16, kk, lane);
#pragma unroll
      for (int ni = 0; ni < 4; ++ni) bv[ni] = frag(Bt, wc + ni*16, kk, lane);
#pragma unroll
      for (int mi = 0; mi < 4; ++mi)
#pragma unroll
      for (int ni = 0; ni < 4; ++ni) acc[mi][ni] = MFMA(av[mi], bv[ni], acc[mi][ni]);
    }
    __syncthreads();
    buf ^= 1;
  }
#pragma unroll
  for (int ni = 0; ni < 4; ++ni){
    int col = wc + ni*16 + (lane & 15);
    float bv = out_b[col];
#pragma unroll
    for (int mi = 0; mi < 4; ++mi)
#pragma unroll
    for (int r = 0; r < 4; ++r){
      size_t m = Rm + wr + mi*16 + ((lane>>4)<<2) + r;
      int t = (int)(m >> 8), b = (int)(m & 255);
      out[(size_t)b*32768 + (size_t)t*256 + col] = acc[mi][ni][r] + bv;
    }
  }
}

extern "C" void kernel_launch(void* const* d_in, const int* in_sizes, int n_in,
                              void* d_out, int out_size, void* d_ws, size_t ws_size,
                              hipStream_t stream) {
  (void)in_sizes; (void)n_in; (void)out_size; (void)ws_size;
  const float* latent = (const float*)d_in[0];
  const float* fc_W   = (const float*)d_in[1];
  const float* fc_b   = (const float*)d_in[2];
  const float* W_ih   = (const float*)d_in[3];
  const float* W_hh   = (const float*)d_in[4];
  const float* b_ih   = (const float*)d_in[5];
  const float* b_hh   = (const float*)d_in[6];
  const float* out_W  = (const float*)d_in[7];
  const float* out_b  = (const float*)d_in[8];
  float* out = (float*)d_out;
  char*  ws  = (char*)d_ws;
  const size_t MB = 1u << 20;
  short* Wt    = (short*)(ws + 0);               //  8 MB  bf16(W_total) permuted+swz
  short* W0    = (short*)(ws + 8*MB);            //  8 MB  bf16(W_hh)    permuted+swz
  short* A0    = (short*)(ws + 16*MB);           //  1 MB  [256][1024hi|1024lo]
  short* A1    = (short*)(ws + 17*MB);           //  1 MB
  float* Cst   = (float*)(ws + 18*MB);           //  1 MB  c state fp32
  float* bias0 = (float*)(ws + 19*MB);           //  16 KB (permuted)
  float* bias1 = (float*)(ws + 19*MB + 65536);   //  16 KB (permuted)
  short* owB   = (short*)(ws + 19*MB + 131072);  // 512 KB bf16(out_W) swz
  short* WihE  = (short*)(ws + 20*MB);           //  4 MB  W_ih hi|lo swz
  short* owTE  = (short*)(ws + 24*MB);           //  1 MB  out_W^T hi|lo swz
  short* latE  = (short*)(ws + 25*MB);           // 512 KB latent hi|lo swz
  short* fcwE  = (short*)(ws + 25*MB + 524288);  //  2 MB  fc_W hi|lo swz
  short* Hh    = (short*)(ws + 28*MB);           // 64 MB  h history bf16 swz

  k_prep<<<1024, 256, 0, stream>>>(W_ih, out_W, latent, fc_W, b_ih, b_hh,
                                   WihE, owTE, latE, fcwE, owB, bias0);
  k_bias1<<<16, 256, 0, stream>>>(W_ih, out_b, bias0, bias1);
  k_wtotal<<<dim3(64,16), 256, 0, stream>>>(WihE, owTE, W_hh, Wt, W0);
  k_h0<<<dim3(4,16), 256, 0, stream>>>(latE, fcwE, fc_b, A0, Cst);
  for (int t = 0; t < 128; ++t){
    const short* Ain = (t & 1) ? A1 : A0;
    short*      Aout = (t & 1) ? A0 : A1;
    k_step<<<dim3(4,64), 256, 0, stream>>>(Ain, t ? Wt : W0, t ? bias1 : bias0,
                                           Cst, Aout, Hh + (size_t)t*256*1024);
  }
  k_y<<<256, 512, 0, stream>>>(Hh, owB, out_b, out);
}

// Round 2
// 2532.378 us; speedup vs baseline: 1.1531x; 1.1531x over previous
//
#include <hip/hip_runtime.h>

// Decoder: h0 = latent@fc_W^T + fc_b ; 128-step LSTM with folded feedback ;
// Y = H_hist @ out_W^T + out_b.
// Step 0 runs as a standalone kernel (needs W_hh/bias0); steps 1..127 run in ONE
// persistent kernel: Wt panel resident in LDS (128KB), h read global->VGPR,
// c-state in registers, per-step sync = 64-WG flag barrier per batch block.
// All bf16 matrices in ws are "swz": element (row,k) stored at k ^ ((row&7)<<3).

typedef __attribute__((ext_vector_type(8))) short bfrag;   // 8 x bf16
typedef __attribute__((ext_vector_type(4))) float f32x4;

#define MFMA(a,b,c) __builtin_amdgcn_mfma_f32_16x16x32_bf16(a,b,c,0,0,0)

__device__ __forceinline__ short f2bf(float x){
  unsigned u = __builtin_bit_cast(unsigned, x);
  u = (u + 0x7fffu + ((u >> 16) & 1u)) >> 16;
  return (short)u;
}
__device__ __forceinline__ float bf2f(short h){
  unsigned u = ((unsigned)(unsigned short)h) << 16;
  return __builtin_bit_cast(float, u);
}

__device__ __forceinline__ void gll16(const void* g, void* l){
  __builtin_amdgcn_global_load_lds((const __attribute__((address_space(1))) void*)g,
                                   (__attribute__((address_space(3))) void*)l, 16, 0, 0);
}

// stage a 64x64 bf16 tile (pre-swizzled global, row-major ld=ldk) into LDS (linear image).
__device__ __forceinline__ void stage_t(const short* gRC, int ldk, short* lds, int lane, int wv){
#pragma unroll
  for (int jj = 0; jj < 2; ++jj){
    int j = wv*2 + jj;
    const short* src = gRC + (size_t)(j*8 + (lane>>3))*ldk + ((lane&7)*8);
    gll16(src, lds + j*512);
  }
}

// MFMA fragment from a 64x64 swizzled LDS tile image.
__device__ __forceinline__ bfrag frag(const short* t, int r, int kk, int lane){
  int row = r + (lane & 15);
  int k0  = (kk<<5) + ((lane>>4)<<3);
  return *(const bfrag*)(t + row*64 + (k0 ^ ((row & 7)<<3)));
}

// generic 64x64-tile GEMM core over 3 K-segments {(0,0),(S,0),(0,S)}, CPS chunks each.
template<int CPS>
__device__ __forceinline__ void core_seg3(const short* Ag, int ldA, const short* Bg, int ldB, int S,
                                          short* As, short* Bs, f32x4 (&acc)[2][2],
                                          int lane, int wv, int wr, int wc){
  int ao = 0, bo = 0;
  stage_t(Ag, ldA, As, lane, wv);
  stage_t(Bg, ldB, Bs, lane, wv);
  __syncthreads();
  int buf = 0;
  const int NCH = 3*CPS;
  for (int c = 0; c < NCH; ++c){
    if (c+1 < NCH){
      int cn = c+1, seg = cn/CPS, kc = cn - seg*CPS;
      ao = kc*64 + (seg==1 ? S : 0);
      bo = kc*64 + (seg==2 ? S : 0);
      stage_t(Ag+ao, ldA, As+(buf^1)*4096, lane, wv);
      stage_t(Bg+bo, ldB, Bs+(buf^1)*4096, lane, wv);
    }
    const short* At = As + buf*4096;
    const short* Bt = Bs + buf*4096;
#pragma unroll
    for (int kk = 0; kk < 2; ++kk){
      bfrag a0 = frag(At, wr,    kk, lane), a1 = frag(At, wr+16, kk, lane);
      bfrag b0 = frag(Bt, wc,    kk, lane), b1 = frag(Bt, wc+16, kk, lane);
      acc[0][0] = MFMA(a0,b0,acc[0][0]); acc[0][1] = MFMA(a0,b1,acc[0][1]);
      acc[1][0] = MFMA(a1,b0,acc[1][0]); acc[1][1] = MFMA(a1,b1,acc[1][1]);
    }
    __syncthreads();
    buf ^= 1;
  }
}

// ---------------- setup kernels ----------------

__global__ void k_prep(const float* __restrict__ W_ih, const float* __restrict__ out_W,
                       const float* __restrict__ latent, const float* __restrict__ fc_W,
                       const float* __restrict__ b_ih, const float* __restrict__ b_hh,
                       short* __restrict__ WihE, short* __restrict__ owTE,
                       short* __restrict__ latE, short* __restrict__ fcwE,
                       short* __restrict__ owB, float* __restrict__ bias0,
                       unsigned* __restrict__ flags){
  int T = blockDim.x*gridDim.x, t0 = blockIdx.x*blockDim.x + threadIdx.x;
  for (int i = t0; i < 8192; i += T) flags[i] = 0u;       // barrier flags
  for (int idx = t0; idx < 4096*256; idx += T){           // W_ih -> [4096][256|256]
    int r = idx >> 8, j = idx & 255;
    float v = W_ih[idx];
    short hi = f2bf(v); short lo = f2bf(v - bf2f(hi));
    int sc = (r&7)<<3;
    WihE[(size_t)r*512 + (j^sc)]        = hi;
    WihE[(size_t)r*512 + ((256+j)^sc)]  = lo;
  }
  for (int idx = t0; idx < 1024*256; idx += T){           // out_W^T -> [1024][256|256]
    int k = idx >> 8, j = idx & 255;
    float v = out_W[(size_t)j*1024 + k];
    short hi = f2bf(v); short lo = f2bf(v - bf2f(hi));
    int sc = (k&7)<<3;
    owTE[(size_t)k*512 + (j^sc)]        = hi;
    owTE[(size_t)k*512 + ((256+j)^sc)]  = lo;
  }
  for (int idx = t0; idx < 256*1024; idx += T){           // out_W -> bf16 [256][1024]
    int o = idx >> 10, k = idx & 1023;
    int sc = (o&7)<<3;
    owB[(size_t)o*1024 + (k^sc)] = f2bf(out_W[idx]);
  }
  for (int idx = t0; idx < 256*512; idx += T){            // latent -> [256][512|512]
    int b = idx >> 9, j = idx & 511;
    float v = latent[idx];
    short hi = f2bf(v); short lo = f2bf(v - bf2f(hi));
    int sc = (b&7)<<3;
    latE[(size_t)b*1024 + (j^sc)]       = hi;
    latE[(size_t)b*1024 + ((512+j)^sc)] = lo;
  }
  for (int idx = t0; idx < 1024*512; idx += T){           // fc_W -> [1024][512|512]
    int n = idx >> 9, j = idx & 511;
    float v = fc_W[idx];
    short hi = f2bf(v); short lo = f2bf(v - bf2f(hi));
    int sc = (n&7)<<3;
    fcwE[(size_t)n*1024 + (j^sc)]       = hi;
    fcwE[(size_t)n*1024 + ((512+j)^sc)] = lo;
  }
  for (int r = t0; r < 4096; r += T){                     // bias0 permuted (u*4+g)
    int rp = ((r & 1023)<<2) | (r >> 10);
    bias0[rp] = b_ih[r] + b_hh[r];
  }
}

__global__ void k_bias1(const float* __restrict__ W_ih, const float* __restrict__ out_b,
                        const float* __restrict__ bias0, float* __restrict__ bias1){
  int r = blockIdx.x*256 + threadIdx.x;            // 4096 threads
  float s = 0.f;
  for (int j = 0; j < 256; ++j) s += W_ih[(size_t)r*256 + j]*out_b[j];
  int rp = ((r & 1023)<<2) | (r >> 10);
  bias1[rp] = bias0[rp] + s;
}

// W_total = W_hh + W_ih@out_W (split-bf16, 3-term); rows permuted (unit*4+gate), swz
__global__ __launch_bounds__(256) void k_wtotal(const short* __restrict__ WihE, const short* __restrict__ owTE,
                                                const float* __restrict__ W_hh,
                                                short* __restrict__ Wt, short* __restrict__ W0){
  __shared__ __align__(16) short As[2*4096];
  __shared__ __align__(16) short Bs[2*4096];
  int tid = threadIdx.x, lane = tid & 63, wv = tid >> 6;
  int wr = (wv>>1)*32, wc = (wv&1)*32;
  int Rm = blockIdx.x*64, Rn = blockIdx.y*64;
  f32x4 acc[2][2] = {};
  core_seg3<4>(WihE + (size_t)Rm*512, 512, owTE + (size_t)Rn*512, 512, 256,
               As, Bs, acc, lane, wv, wr, wc);
#pragma unroll
  for (int mi = 0; mi < 2; ++mi)
#pragma unroll
  for (int ni = 0; ni < 2; ++ni)
#pragma unroll
  for (int r = 0; r < 4; ++r){
    int row = Rm + wr + mi*16 + ((lane>>4)<<2) + r;
    int col = Rn + wc + ni*16 + (lane & 15);
    float whh = W_hh[(size_t)row*1024 + col];
    int rp = ((row & 1023)<<2) | (row >> 10);
    int cs = col ^ ((rp&7)<<3);
    Wt[(size_t)rp*1024 + cs] = f2bf(acc[mi][ni][r] + whh);
    W0[(size_t)rp*1024 + cs] = f2bf(whh);
  }
}

// h0 = latent@fc_W^T + fc_b (split-bf16 3-term); writes A0 (hi|lo) and zeroes c
__global__ __launch_bounds__(256) void k_h0(const short* __restrict__ latE, const short* __restrict__ fcwE,
                                            const float* __restrict__ fc_b,
                                            short* __restrict__ A0, float* __restrict__ Cst){
  __shared__ __align__(16) short As[2*4096];
  __shared__ __align__(16) short Bs[2*4096];
  int tid = threadIdx.x, lane = tid & 63, wv = tid >> 6;
  int wr = (wv>>1)*32, wc = (wv&1)*32;
  int Rm = blockIdx.x*64, Rn = blockIdx.y*64;
  f32x4 acc[2][2] = {};
  core_seg3<8>(latE + (size_t)Rm*1024, 1024, fcwE + (size_t)Rn*1024, 1024, 512,
               As, Bs, acc, lane, wv, wr, wc);
#pragma unroll
  for (int mi = 0; mi < 2; ++mi)
#pragma unroll
  for (int ni = 0; ni < 2; ++ni)
#pragma unroll
  for (int r = 0; r < 4; ++r){
    int row = Rm + wr + mi*16 + ((lane>>4)<<2) + r;   // batch
    int col = Rn + wc + ni*16 + (lane & 15);          // unit
    float h = acc[mi][ni][r] + fc_b[col];
    short hi = f2bf(h); short lo = f2bf(h - bf2f(hi));
    int sc = (row&7)<<3;
    A0[(size_t)row*2048 + (col^sc)]          = hi;
    A0[(size_t)row*2048 + ((1024+col)^sc)]   = lo;
    Cst[(size_t)row*1024 + col] = 0.f;
  }
}

// ---------------- step 0 (uses W_hh / bias0, c=0 -> writes Cst, A1, Ht[0]) ----------------
__global__ __launch_bounds__(256) void k_step(const short* __restrict__ A, const short* __restrict__ Bw,
                                              const float* __restrict__ bias, float* __restrict__ Cst,
                                              short* __restrict__ Anext, short* __restrict__ Ht){
  __shared__ __align__(16) short Hs[2*4096];
  __shared__ __align__(16) short Ls[2*4096];
  __shared__ __align__(16) short Bs[2*4096];
  __shared__ __align__(16) float Lacc[64*68];
  int tid = threadIdx.x, lane = tid & 63, wv = tid >> 6;
  int wr = (wv>>1)*32, wc = (wv&1)*32;
  int Rm = blockIdx.x*64;
  int Rn = blockIdx.y*64;
  const short* Ab = A  + (size_t)Rm*2048;
  const short* Bb = Bw + (size_t)Rn*1024;
  f32x4 acc[2][2] = {};
  stage_t(Ab,        2048, Hs, lane, wv);
  stage_t(Ab + 1024, 2048, Ls, lane, wv);
  stage_t(Bb,        1024, Bs, lane, wv);
  __syncthreads();
  int buf = 0;
  for (int c = 0; c < 16; ++c){
    if (c+1 < 16){
      int k = (c+1)*64;
      stage_t(Ab + k,        2048, Hs + (buf^1)*4096, lane, wv);
      stage_t(Ab + 1024 + k, 2048, Ls + (buf^1)*4096, lane, wv);
      stage_t(Bb + k,        1024, Bs + (buf^1)*4096, lane, wv);
    }
    const short* Htile = Hs + buf*4096;
    const short* Ltile = Ls + buf*4096;
    const short* Btile = Bs + buf*4096;
#pragma unroll
    for (int kk = 0; kk < 2; ++kk){
      bfrag b0 = frag(Btile, wc,    kk, lane), b1 = frag(Btile, wc+16, kk, lane);
      bfrag h0 = frag(Htile, wr,    kk, lane), h1 = frag(Htile, wr+16, kk, lane);
      bfrag l0 = frag(Ltile, wr,    kk, lane), l1 = frag(Ltile, wr+16, kk, lane);
      acc[0][0] = MFMA(h0,b0,acc[0][0]); acc[0][1] = MFMA(h0,b1,acc[0][1]);
      acc[1][0] = MFMA(h1,b0,acc[1][0]); acc[1][1] = MFMA(h1,b1,acc[1][1]);
      acc[0][0] = MFMA(l0,b0,acc[0][0]); acc[0][1] = MFMA(l0,b1,acc[0][1]);
      acc[1][0] = MFMA(l1,b0,acc[1][0]); acc[1][1] = MFMA(l1,b1,acc[1][1]);
    }
    __syncthreads();
    buf ^= 1;
  }
#pragma unroll
  for (int ni = 0; ni < 2; ++ni){
    int col = wc + ni*16 + (lane & 15);
    float bv = bias[Rn + col];
#pragma unroll
    for (int mi = 0; mi < 2; ++mi)
#pragma unroll
    for (int r = 0; r < 4; ++r){
      int row = wr + mi*16 + ((lane>>4)<<2) + r;
      Lacc[row*68 + col] = acc[mi][ni][r] + bv;
    }
  }
  __syncthreads();
#pragma unroll
  for (int i = 0; i < 4; ++i){
    int cell = i*256 + tid;
    int m = cell >> 4, u = cell & 15;
    float4 g4 = *(const float4*)&Lacc[m*68 + u*4];
    float I = 1.f/(1.f + __expf(-g4.x));
    float F = 1.f/(1.f + __expf(-g4.y));
    float G = tanhf(g4.z);
    float O = 1.f/(1.f + __expf(-g4.w));
    int gm = Rm + m, gu = (Rn>>2) + u;
    float co = Cst[(size_t)gm*1024 + gu];
    float cn = F*co + I*G;
    float hn = O*tanhf(cn);
    Cst[(size_t)gm*1024 + gu] = cn;
    short hi = f2bf(hn); short lo = f2bf(hn - bf2f(hi));
    int sc = (gm&7)<<3;
    Anext[(size_t)gm*2048 + (gu^sc)]        = hi;
    Anext[(size_t)gm*2048 + ((1024+gu)^sc)] = lo;
    Ht[(size_t)gm*1024 + (gu^sc)]           = hi;
  }
}

// ---------------- persistent kernel: steps 1..127 ----------------
// grid 256 WGs x 256 thr. WG (b,g): batch rows 64b..+64, permuted gate cols 64g..+64
// (= units 16g..+16). Wt panel resident in LDS; h read global->VGPR; c in regs.
__global__ __launch_bounds__(256, 1) void k_persist(const short* __restrict__ Wt,
    const float* __restrict__ bias1, const float* __restrict__ Cst,
    short* __restrict__ A0, short* __restrict__ A1, short* __restrict__ Hh,
    unsigned* __restrict__ flags){
  __shared__ __align__(16) short Bp[64*1024];       // 128 KB resident W panel
  __shared__ __align__(16) float Lacc[4][16*68];    // per-wave epilogue exchange
  int tid = threadIdx.x, lane = tid & 63, wv = tid >> 6;
  int wg = blockIdx.x;
  int b = wg & 3, g = wg >> 2;
  int Rm = b*64, Rn = g*64;

  // ---- load resident B panel (linear 128KB copy, global pre-swizzled) ----
  {
    const short* src = Wt + (size_t)Rn*1024;
#pragma unroll
    for (int j = 0; j < 32; ++j){
      int o = (j*256 + wv*64)*8;                    // this wave's 1KB chunk (shorts)
      gll16(src + o + lane*8, Bp + o);              // HW scatters lane*16B
    }
  }

  // ---- per-lane constants ----
  int kgl = (lane>>4)<<3;                           // k sub-group for MFMA operand
  int arow = Rm + wv*16 + (lane & 15);              // A row this lane loads
  int sca  = (arow & 7)<<3;
  int bB[4], sB[4];
  float bw[4];
#pragma unroll
  for (int ni = 0; ni < 4; ++ni){
    int rowb = ni*16 + (lane & 15);                 // gate col (panel-local)
    bB[ni] = rowb*1024;
    sB[ni] = (rowb & 7)<<3;
    bw[ni] = bias1[Rn + rowb];
  }
  // epilogue cell ownership: row er, unit quad u0
  int er = lane >> 2, u0 = (lane & 3)<<2;
  int gm = Rm + wv*16 + er;
  int gu0 = g*16 + u0;
  float c0_ = Cst[(size_t)gm*1024 + gu0 + 0];
  float c1_ = Cst[(size_t)gm*1024 + gu0 + 1];
  float c2_ = Cst[(size_t)gm*1024 + gu0 + 2];
  float c3_ = Cst[(size_t)gm*1024 + gu0 + 3];
  int scE = (gm & 7)<<3;
  int posE = gu0 ^ scE;                             // 4-aligned, contiguous quad
  const size_t rowOff = (size_t)gm*2048;

  __syncthreads();                                  // B panel ready

  for (int t = 1; t < 128; ++t){
    const short* Arow = ((t & 1) ? A1 : A0) + (size_t)arow*2048;
    short* Aout = (t & 1) ? A0 : A1;
    f32x4 acc0 = {}, acc1 = {}, acc2 = {}, acc3 = {};
#pragma unroll 4
    for (int ks = 0; ks < 32; ++ks){
      int kg = ks*32 + kgl;
      bfrag ah = *(const bfrag*)(Arow + (kg ^ sca));
      bfrag al = *(const bfrag*)(Arow + 1024 + (kg ^ sca));
      bfrag q0 = *(const bfrag*)(Bp + bB[0] + (kg ^ sB[0]));
      bfrag q1 = *(const bfrag*)(Bp + bB[1] + (kg ^ sB[1]));
      bfrag q2 = *(const bfrag*)(Bp + bB[2] + (kg ^ sB[2]));
      bfrag q3 = *(const bfrag*)(Bp + bB[3] + (kg ^ sB[3]));
      acc0 = MFMA(ah, q0, acc0); acc1 = MFMA(ah, q1, acc1);
      acc2 = MFMA(ah, q2, acc2); acc3 = MFMA(ah, q3, acc3);
      acc0 = MFMA(al, q0, acc0); acc1 = MFMA(al, q1, acc1);
      acc2 = MFMA(al, q2, acc2); acc3 = MFMA(al, q3, acc3);
    }
    // ---- wave-local gate exchange (no workgroup barrier) ----
    float* Lw = &Lacc[wv][0];
#pragma unroll
    for (int r = 0; r < 4; ++r){
      int rr = ((lane>>4)<<2) + r;
      Lw[rr*68 + 0*16 + (lane & 15)] = acc0[r] + bw[0];
      Lw[rr*68 + 1*16 + (lane & 15)] = acc1[r] + bw[1];
      Lw[rr*68 + 2*16 + (lane & 15)] = acc2[r] + bw[2];
      Lw[rr*68 + 3*16 + (lane & 15)] = acc3[r] + bw[3];
    }
    __asm volatile("s_waitcnt lgkmcnt(0)" ::: "memory");
    // ---- LSTM cell: 4 units of one row per lane ----
    short4 sh, sl;
#pragma unroll
    for (int u = 0; u < 4; ++u){
      float4 q = *(const float4*)&Lw[er*68 + (u0 + u)*4];
      float I = 1.f/(1.f + __expf(-q.x));
      float F = 1.f/(1.f + __expf(-q.y));
      float G = tanhf(q.z);
      float O = 1.f/(1.f + __expf(-q.w));
      float cv = (u==0)? c0_ : (u==1)? c1_ : (u==2)? c2_ : c3_;
      float cn = F*cv + I*G;
      if (u==0) c0_ = cn; else if (u==1) c1_ = cn; else if (u==2) c2_ = cn; else c3_ = cn;
      float hn = O*tanhf(cn);
      short hi = f2bf(hn);
      ((short*)&sh)[u] = hi;
      ((short*)&sl)[u] = f2bf(hn - bf2f(hi));
    }
    *(short4*)(Aout + rowOff + posE)        = sh;
    *(short4*)(Aout + rowOff + 1024 + posE) = sl;
    *(short4*)(Hh + (size_t)t*262144 + (size_t)gm*1024 + posE) = sh;

    if (t < 127){
      __syncthreads();                              // all stores of this WG drained
      if (tid == 0)
        __hip_atomic_store(flags + (size_t)wg*32, (unsigned)t,
                           __ATOMIC_RELEASE, __HIP_MEMORY_SCOPE_AGENT);
      if (wv == 0){
        const unsigned* fp = flags + (size_t)(lane*4 + b)*32;  // 64 WGs of my b-group
        while (__hip_atomic_load(fp, __ATOMIC_RELAXED, __HIP_MEMORY_SCOPE_AGENT)
               < (unsigned)t) {}
        __builtin_amdgcn_fence(__ATOMIC_ACQUIRE, "agent");
      }
      __syncthreads();
    }
  }
}

// ---------------- final Y GEMM ----------------
__global__ __launch_bounds__(512) void k_y(const short* __restrict__ Hh, const short* __restrict__ owB,
                                           const float* __restrict__ out_b, float* __restrict__ out){
  __shared__ __align__(16) short As[2*8192];
  __shared__ __align__(16) short Bs[2*16384];
  int tid = threadIdx.x, lane = tid & 63, wv = tid >> 6;
  int wr = (wv>>2)*64, wc = (wv&3)*64;
  size_t Rm = (size_t)blockIdx.x * 128;
  const short* Ab = Hh + Rm*1024;
  f32x4 acc[4][4] = {};
  auto stA = [&](int c, short* dst){
#pragma unroll
    for (int jj = 0; jj < 2; ++jj){ int j = wv*2 + jj;
      gll16(Ab + (size_t)(j*8 + (lane>>3))*1024 + c*64 + (lane&7)*8, dst + j*512); }
  };
  auto stB = [&](int c, short* dst){
#pragma unroll
    for (int jj = 0; jj < 4; ++jj){ int j = wv*4 + jj;
      gll16(owB + (size_t)(j*8 + (lane>>3))*1024 + c*64 + (lane&7)*8, dst + j*512); }
  };
  stA(0, As); stB(0, Bs);
  __syncthreads();
  int buf = 0;
  for (int c = 0; c < 16; ++c){
    if (c+1 < 16){ stA(c+1, As + (buf^1)*8192); stB(c+1, Bs + (buf^1)*16384); }
    const short* At = As + buf*8192;
    const short* Bt = Bs + buf*16384;
#pragma unroll
    for (int kk = 0; kk < 2; ++kk){
      bfrag av[4], bv[4];
#pragma unroll
      for (int mi = 0; mi < 4; ++mi) av[mi] = frag(At, wr + mi*16, kk, lane);
#pragma unroll
      for (int ni = 0; ni < 4; ++ni) bv[ni] = frag(Bt, wc + ni*16, kk, lane);
#pragma unroll
      for (int mi = 0; mi < 4; ++mi)
#pragma unroll
      for (int ni = 0; ni < 4; ++ni) acc[mi][ni] = MFMA(av[mi], bv[ni], acc[mi][ni]);
    }
    __syncthreads();
    buf ^= 1;
  }
#pragma unroll
  for (int ni = 0; ni < 4; ++ni){
    int col = wc + ni*16 + (lane & 15);
    float bv = out_b[col];
#pragma unroll
    for (int mi = 0; mi < 4; ++mi)
#pragma unroll
    for (int r = 0; r < 4; ++r){
      size_t m = Rm + wr + mi*16 + ((lane>>4)<<2) + r;
      int t = (int)(m >> 8), bb = (int)(m & 255);
      out[(size_t)bb*32768 + (size_t)t*256 + col] = acc[mi][ni][r] + bv;
    }
  }
}

extern "C" void kernel_launch(void* const* d_in, const int* in_sizes, int n_in,
                              void* d_out, int out_size, void* d_ws, size_t ws_size,
                              hipStream_t stream) {
  (void)in_sizes; (void)n_in; (void)out_size; (void)ws_size;
  const float* latent = (const float*)d_in[0];
  const float* fc_W   = (const float*)d_in[1];
  const float* fc_b   = (const float*)d_in[2];
  const float* W_ih   = (const float*)d_in[3];
  const float* W_hh   = (const float*)d_in[4];
  const float* b_ih   = (const float*)d_in[5];
  const float* b_hh   = (const float*)d_in[6];
  const float* out_W  = (const float*)d_in[7];
  const float* out_b  = (const float*)d_in[8];
  float* out = (float*)d_out;
  char*  ws  = (char*)d_ws;
  const size_t MB = 1u << 20;
  short* Wt    = (short*)(ws + 0);               //  8 MB  bf16(W_total) permuted+swz
  short* W0    = (short*)(ws + 8*MB);            //  8 MB  bf16(W_hh)    permuted+swz
  short* A0    = (short*)(ws + 16*MB);           //  1 MB  [256][1024hi|1024lo]
  short* A1    = (short*)(ws + 17*MB);           //  1 MB
  float* Cst   = (float*)(ws + 18*MB);           //  1 MB  c state fp32
  float* bias0 = (float*)(ws + 19*MB);           //  16 KB (permuted)
  float* bias1 = (float*)(ws + 19*MB + 65536);   //  16 KB (permuted)
  short* owB   = (short*)(ws + 19*MB + 131072);  // 512 KB bf16(out_W) swz
  short* WihE  = (short*)(ws + 20*MB);           //  4 MB  W_ih hi|lo swz
  short* owTE  = (short*)(ws + 24*MB);           //  1 MB  out_W^T hi|lo swz
  short* latE  = (short*)(ws + 25*MB);           // 512 KB latent hi|lo swz
  short* fcwE  = (short*)(ws + 25*MB + 524288);  //  2 MB  fc_W hi|lo swz
  unsigned* flg= (unsigned*)(ws + 27*MB + 524288); // 32 KB barrier flags
  short* Hh    = (short*)(ws + 28*MB);           // 64 MB  h history bf16 swz

  k_prep<<<1024, 256, 0, stream>>>(W_ih, out_W, latent, fc_W, b_ih, b_hh,
                                   WihE, owTE, latE, fcwE, owB, bias0, flg);
  k_bias1<<<16, 256, 0, stream>>>(W_ih, out_b, bias0, bias1);
  k_wtotal<<<dim3(64,16), 256, 0, stream>>>(WihE, owTE, W_hh, Wt, W0);
  k_h0<<<dim3(4,16), 256, 0, stream>>>(latE, fcwE, fc_b, A0, Cst);
  k_step<<<dim3(4,64), 256, 0, stream>>>(A0, W0, bias0, Cst, A1, Hh);   // t = 0
  k_persist<<<256, 256, 0, stream>>>(Wt, bias1, Cst, A0, A1, Hh, flg);  // t = 1..127
  k_y<<<256, 512, 0, stream>>>(Hh, owB, out_b, out);
}

// Round 3
// 1424.349 us; speedup vs baseline: 2.0501x; 1.7779x over previous
//
#include <hip/hip_runtime.h>

// Decoder: h0 = latent@fc_W^T + fc_b ; 128-step LSTM with folded feedback
// (x_t = y_{t-1} folded into W_total = W_hh + W_ih@out_W) ; Y = H_hist@out_W^T + out_b.
// All fp16. k_persist runs ALL 128 steps: 8 XCD-local chains of 32 batch rows,
// 32 WGs/chain, weights resident in VGPRs (frag-block layout), A staged to LDS
// per step, c-state in registers, per-step 32-WG flag barrier.
// Row-major fp16 ws matrices are "swz": elem (row,k) stored at k ^ ((row&7)<<3).

typedef __attribute__((ext_vector_type(8))) _Float16 f16x8;
typedef __attribute__((ext_vector_type(4))) float f32x4;

#define MFMA16(a,b,c) __builtin_amdgcn_mfma_f32_16x16x32_f16(a,b,c,0,0,0)

__device__ __forceinline__ short f2h(float x){
  return __builtin_bit_cast(short, (_Float16)x);
}
__device__ __forceinline__ unsigned pack2h(float a, float b){
  unsigned short ua = __builtin_bit_cast(unsigned short, (_Float16)a);
  unsigned short ub = __builtin_bit_cast(unsigned short, (_Float16)b);
  return (unsigned)ua | ((unsigned)ub << 16);
}

__device__ __forceinline__ void gll16(const void* g, void* l){
  __builtin_amdgcn_global_load_lds((const __attribute__((address_space(1))) void*)g,
                                   (__attribute__((address_space(3))) void*)l, 16, 0, 0);
}

// stage a 64x64 fp16 tile (pre-swizzled global, row-major ld=ldk) into LDS (linear image)
__device__ __forceinline__ void stage_t(const short* gRC, int ldk, short* lds, int lane, int wv){
#pragma unroll
  for (int jj = 0; jj < 2; ++jj){
    int j = wv*2 + jj;
    const short* src = gRC + (size_t)(j*8 + (lane>>3))*ldk + ((lane&7)*8);
    gll16(src, lds + j*512);
  }
}

// MFMA A/B fragment from a 64x64 swizzled LDS tile image
__device__ __forceinline__ f16x8 fragh(const short* t, int r, int kk, int lane){
  int row = r + (lane & 15);
  int k0  = (kk<<5) + ((lane>>4)<<3);
  return *(const f16x8*)(t + row*64 + (k0 ^ ((row & 7)<<3)));
}

// generic 64x64-tile fp16 GEMM core, CH k-chunks of 64
template<int CH>
__device__ __forceinline__ void core_k(const short* Ag, const short* Bg, int ldk,
                                       short* As, short* Bs, f32x4 (&acc)[2][2],
                                       int lane, int wv, int wr, int wc){
  stage_t(Ag, ldk, As, lane, wv);
  stage_t(Bg, ldk, Bs, lane, wv);
  __syncthreads();
  int buf = 0;
  for (int c = 0; c < CH; ++c){
    if (c+1 < CH){
      stage_t(Ag + (c+1)*64, ldk, As + (buf^1)*4096, lane, wv);
      stage_t(Bg + (c+1)*64, ldk, Bs + (buf^1)*4096, lane, wv);
    }
    const short* At = As + buf*4096;
    const short* Bt = Bs + buf*4096;
#pragma unroll
    for (int kk = 0; kk < 2; ++kk){
      f16x8 a0 = fragh(At, wr,    kk, lane), a1 = fragh(At, wr+16, kk, lane);
      f16x8 b0 = fragh(Bt, wc,    kk, lane), b1 = fragh(Bt, wc+16, kk, lane);
      acc[0][0] = MFMA16(a0,b0,acc[0][0]); acc[0][1] = MFMA16(a0,b1,acc[0][1]);
      acc[1][0] = MFMA16(a1,b0,acc[1][0]); acc[1][1] = MFMA16(a1,b1,acc[1][1]);
    }
    __syncthreads();
    buf ^= 1;
  }
}

// ---------------- setup ----------------
// Weight frag-block layout (for VGPR residency + direct frag loads):
// block(c,s) = 512 shorts at ((c*32)+s)*512 ; within: lane l covers
// (gatecol p = 16c + (l&15), k = 32s + (l>>4)*8 .. +8). p is the PERMUTED
// gate index p = ((r&1023)<<2) | (r>>10)  (unit*4 + gate, torch order i,f,g,o).

__global__ void k_prep(const float* __restrict__ W_ih, const float* __restrict__ out_W,
                       const float* __restrict__ latent, const float* __restrict__ fc_W,
                       const float* __restrict__ W_hh,
                       const float* __restrict__ b_ih, const float* __restrict__ b_hh,
                       short* __restrict__ WihF, short* __restrict__ owT,
                       short* __restrict__ owB, short* __restrict__ latF,
                       short* __restrict__ fcwF, short* __restrict__ W0F,
                       float* __restrict__ bias0, unsigned* __restrict__ flags){
  int T = blockDim.x*gridDim.x, t0 = blockIdx.x*blockDim.x + threadIdx.x;
  for (int i = t0; i < 8192; i += T) flags[i] = 0u;
  for (int idx = t0; idx < 4096*256; idx += T){    // WihF [4096][256] swz
    int r = idx >> 8, j = idx & 255;
    WihF[(size_t)r*256 + (j ^ ((r&7)<<3))] = f2h(W_ih[idx]);
  }
  for (int idx = t0; idx < 1024*256; idx += T){    // owT [1024][256]: owT[c][j]=out_W[j][c]
    int c = idx >> 8, j = idx & 255;
    owT[(size_t)c*256 + (j ^ ((c&7)<<3))] = f2h(out_W[(size_t)j*1024 + c]);
  }
  for (int idx = t0; idx < 256*1024; idx += T){    // owB [256][1024] swz
    int o = idx >> 10, k = idx & 1023;
    owB[(size_t)o*1024 + (k ^ ((o&7)<<3))] = f2h(out_W[idx]);
  }
  for (int idx = t0; idx < 256*512; idx += T){     // latF [256][512] swz
    int b = idx >> 9, j = idx & 511;
    latF[(size_t)b*512 + (j ^ ((b&7)<<3))] = f2h(latent[idx]);
  }
  for (int idx = t0; idx < 1024*512; idx += T){    // fcwF [1024][512] swz
    int n = idx >> 9, j = idx & 511;
    fcwF[(size_t)n*512 + (j ^ ((n&7)<<3))] = f2h(fc_W[idx]);
  }
  for (int idx = t0; idx < 4096*1024; idx += T){   // W0F = fp16(W_hh) frag blocks
    int r = idx >> 10, k = idx & 1023;
    int p = ((r & 1023)<<2) | (r >> 10);
    size_t a = ((size_t)(p>>4)*32 + (k>>5))*512 + ((size_t)((((k>>3)&3)<<4)|(p&15)))*8 + (k&7);
    W0F[a] = f2h(W_hh[idx]);
  }
  for (int r = t0; r < 4096; r += T){
    int rp = ((r & 1023)<<2) | (r >> 10);
    bias0[rp] = b_ih[r] + b_hh[r];
  }
}

__global__ void k_bias1(const float* __restrict__ W_ih, const float* __restrict__ out_b,
                        const float* __restrict__ bias0, float* __restrict__ bias1){
  int r = blockIdx.x*256 + threadIdx.x;            // 4096 threads
  float s = 0.f;
  for (int j = 0; j < 256; ++j) s += W_ih[(size_t)r*256 + j]*out_b[j];
  int rp = ((r & 1023)<<2) | (r >> 10);
  bias1[rp] = bias0[rp] + s;
}

// WtF = fp16(W_hh + W_ih@out_W), frag-block layout
__global__ __launch_bounds__(256) void k_wtotal(const short* __restrict__ WihF,
                                                const short* __restrict__ owT,
                                                const float* __restrict__ W_hh,
                                                short* __restrict__ WtF){
  __shared__ __align__(16) short As[2*4096];
  __shared__ __align__(16) short Bs[2*4096];
  int tid = threadIdx.x, lane = tid & 63, wv = tid >> 6;
  int wr = (wv>>1)*32, wc = (wv&1)*32;
  int Rm = blockIdx.x*64, Rn = blockIdx.y*64;
  f32x4 acc[2][2] = {};
  core_k<4>(WihF + (size_t)Rm*256, owT + (size_t)Rn*256, 256, As, Bs, acc, lane, wv, wr, wc);
#pragma unroll
  for (int mi = 0; mi < 2; ++mi)
#pragma unroll
  for (int ni = 0; ni < 2; ++ni)
#pragma unroll
  for (int r = 0; r < 4; ++r){
    int row = Rm + wr + mi*16 + ((lane>>4)<<2) + r;   // gate row
    int col = Rn + wc + ni*16 + (lane & 15);          // k
    float v = acc[mi][ni][r] + W_hh[(size_t)row*1024 + col];
    int p = ((row & 1023)<<2) | (row >> 10);
    size_t a = ((size_t)(p>>4)*32 + (col>>5))*512 + ((size_t)((((col>>3)&3)<<4)|(p&15)))*8 + (col&7);
    WtF[a] = f2h(v);
  }
}

// h0 = latent@fc_W^T + fc_b -> A0 fp16 swz
__global__ __launch_bounds__(256) void k_h0(const short* __restrict__ latF,
                                            const short* __restrict__ fcwF,
                                            const float* __restrict__ fc_b,
                                            short* __restrict__ A0){
  __shared__ __align__(16) short As[2*4096];
  __shared__ __align__(16) short Bs[2*4096];
  int tid = threadIdx.x, lane = tid & 63, wv = tid >> 6;
  int wr = (wv>>1)*32, wc = (wv&1)*32;
  int Rm = blockIdx.x*64, Rn = blockIdx.y*64;
  f32x4 acc[2][2] = {};
  core_k<8>(latF + (size_t)Rm*512, fcwF + (size_t)Rn*512, 512, As, Bs, acc, lane, wv, wr, wc);
#pragma unroll
  for (int mi = 0; mi < 2; ++mi)
#pragma unroll
  for (int ni = 0; ni < 2; ++ni)
#pragma unroll
  for (int r = 0; r < 4; ++r){
    int row = Rm + wr + mi*16 + ((lane>>4)<<2) + r;   // batch
    int col = Rn + wc + ni*16 + (lane & 15);          // unit
    float h = acc[mi][ni][r] + fc_b[col];
    A0[(size_t)row*1024 + (col ^ ((row&7)<<3))] = f2h(h);
  }
}

// ---------------- persistent kernel: steps 0..127 ----------------
// 256 WGs x 512 thr. chain = wg&7 (XCD-local under round-robin), gw = wg>>3.
// WG: batch rows chain*32..+32, permuted gate cols gw*128..+128 (= units gw*32..+32).
// Wave (wn=wv&3, kh=wv>>2): cols wn*32..+32 of the WG block, k-half kh*512.
__global__ __launch_bounds__(512, 2) void k_persist(
    const short* __restrict__ WtF, const short* __restrict__ W0F,
    const float* __restrict__ bias0, const float* __restrict__ bias1,
    short* __restrict__ A0, short* __restrict__ A1, short* __restrict__ Hh,
    unsigned* __restrict__ flags){
  __shared__ __align__(16) short Asl[32*1024];      // 64 KB chain A slice (swz image)
  __shared__ __align__(16) float Lg0[32*132];       // kh=0 partial gates
  __shared__ __align__(16) float Lg1[32*132];       // kh=1 partial gates
  const int tid = threadIdx.x, lane = tid & 63, wv = tid >> 6;
  const int wg = blockIdx.x;
  const int chain = wg & 7, gw = wg >> 3;
  const int wn = wv & 3, kh = wv >> 2;
  const int cbase = gw*8 + wn*2, sbase = kh*16;

  // resident W_total fragments (128 VGPRs)
  f16x8 Breg[2][16];
  {
    const short* src = WtF + ((size_t)cbase*32 + sbase)*512 + lane*8;
#pragma unroll
    for (int cf = 0; cf < 2; ++cf)
#pragma unroll
      for (int s = 0; s < 16; ++s)
        Breg[cf][s] = *(const f16x8*)(src + (size_t)(cf*32 + s)*512);
  }
  const short* W0base = W0F + ((size_t)cbase*32 + sbase)*512 + lane*8;

  // A-frag addressing
  const int r0 = lane & 15;
  const int kq = (lane>>4)<<3;
  const int sw = (r0 & 7) << 3;

  // cell phase: thread (er,up) owns rows er, units 2up,2up+1 of this WG
  const int er = tid >> 4, up = tid & 15;
  const int grow = chain*32 + er;
  const int swE = (grow & 7) << 3;
  const int ugl = gw*32 + 2*up;                     // even global unit
  const int posE = ugl ^ swE;                       // pair stays adjacent, 4B aligned
  const f32x4 b0qA = *(const f32x4*)(bias0 + gw*128 + 8*up);
  const f32x4 b0qB = *(const f32x4*)(bias0 + gw*128 + 8*up + 4);
  const f32x4 b1qA = *(const f32x4*)(bias1 + gw*128 + 8*up);
  const f32x4 b1qB = *(const f32x4*)(bias1 + gw*128 + 8*up + 4);
  float cA = 0.f, cB = 0.f;

  for (int t = 0; t < 128; ++t){
    const short* Ain = (t & 1) ? A1 : A0;
    short* Aout = (t & 1) ? A0 : A1;
    // stage chain A slice: 64 x 1KB gll16, 8 per wave
#pragma unroll
    for (int q = 0; q < 8; ++q){
      int i = wv*8 + q;
      gll16(Ain + (size_t)(chain*32 + (i>>1))*1024 + (i&1)*512 + lane*8, Asl + i*512);
    }
    __syncthreads();

    f32x4 acc[2][2] = {};
    const short* Ar0 = Asl + r0*1024;
    const short* Ar1 = Asl + (16 + r0)*1024;
    if (t == 0){
#pragma unroll
      for (int s = 0; s < 16; ++s){
        int k = (sbase + s)*32 + kq;
        f16x8 w0 = *(const f16x8*)(W0base + (size_t)(0*32 + s)*512);
        f16x8 w1 = *(const f16x8*)(W0base + (size_t)(1*32 + s)*512);
        f16x8 a0 = *(const f16x8*)(Ar0 + (k ^ sw));
        f16x8 a1 = *(const f16x8*)(Ar1 + (k ^ sw));
        acc[0][0] = MFMA16(a0, w0, acc[0][0]);
        acc[0][1] = MFMA16(a0, w1, acc[0][1]);
        acc[1][0] = MFMA16(a1, w0, acc[1][0]);
        acc[1][1] = MFMA16(a1, w1, acc[1][1]);
      }
    } else {
#pragma unroll
      for (int s = 0; s < 16; ++s){
        int k = (sbase + s)*32 + kq;
        f16x8 a0 = *(const f16x8*)(Ar0 + (k ^ sw));
        f16x8 a1 = *(const f16x8*)(Ar1 + (k ^ sw));
        acc[0][0] = MFMA16(a0, Breg[0][s], acc[0][0]);
        acc[0][1] = MFMA16(a0, Breg[1][s], acc[0][1]);
        acc[1][0] = MFMA16(a1, Breg[0][s], acc[1][0]);
        acc[1][1] = MFMA16(a1, Breg[1][s], acc[1][1]);
      }
    }
    // partial gates -> LDS
    float* Lg = kh ? Lg1 : Lg0;
#pragma unroll
    for (int rf = 0; rf < 2; ++rf)
#pragma unroll
    for (int cf = 0; cf < 2; ++cf)
#pragma unroll
    for (int j = 0; j < 4; ++j)
      Lg[(rf*16 + ((lane>>4)<<2) + j)*132 + wn*32 + cf*16 + r0] = acc[rf][cf][j];
    __syncthreads();
    // LSTM cell (k-half reduction + bias + nonlinearities), c in registers
    {
      f32x4 gA = *(const f32x4*)(Lg0 + er*132 + 8*up);
      f32x4 gB = *(const f32x4*)(Lg0 + er*132 + 8*up + 4);
      f32x4 hA = *(const f32x4*)(Lg1 + er*132 + 8*up);
      f32x4 hB = *(const f32x4*)(Lg1 + er*132 + 8*up + 4);
      gA = gA + hA + (t ? b1qA : b0qA);
      gB = gB + hB + (t ? b1qB : b0qB);
      float I0 = 1.f/(1.f+__expf(-gA[0])), F0 = 1.f/(1.f+__expf(-gA[1]));
      float G0 = tanhf(gA[2]),             O0 = 1.f/(1.f+__expf(-gA[3]));
      float I1 = 1.f/(1.f+__expf(-gB[0])), F1 = 1.f/(1.f+__expf(-gB[1]));
      float G1 = tanhf(gB[2]),             O1 = 1.f/(1.f+__expf(-gB[3]));
      cA = F0*cA + I0*G0;  float h0v = O0*tanhf(cA);
      cB = F1*cB + I1*G1;  float h1v = O1*tanhf(cB);
      unsigned pk = pack2h(h0v, h1v);
      *(unsigned*)(Aout + (size_t)grow*1024 + posE) = pk;
      *(unsigned*)(Hh + (size_t)t*262144 + (size_t)grow*1024 + posE) = pk;
    }
    if (t < 127){
      __syncthreads();                              // all stores of this WG issued+drained
      if (tid == 0)
        __hip_atomic_store(flags + (size_t)wg*32, (unsigned)(t+1),
                           __ATOMIC_RELEASE, __HIP_MEMORY_SCOPE_AGENT);
      if (wv == 0){
        const unsigned* fp = flags + (size_t)(chain + 8*(lane & 31))*32;
        while (__hip_atomic_load(fp, __ATOMIC_RELAXED, __HIP_MEMORY_SCOPE_AGENT)
               < (unsigned)(t+1)) {}
        __builtin_amdgcn_fence(__ATOMIC_ACQUIRE, "agent");
      }
      __syncthreads();
    }
  }
}

// ---------------- final Y GEMM ----------------
// out[b][t][o] = Hh[t*256+b] . owB[o] + out_b[o] ; tile 128x256, 8 waves
__global__ __launch_bounds__(512) void k_y(const short* __restrict__ Hh,
                                           const short* __restrict__ owB,
                                           const float* __restrict__ out_b,
                                           float* __restrict__ out){
  __shared__ __align__(16) short As[2*8192];    // [128][64] x2
  __shared__ __align__(16) short Bs[2*16384];   // [256][64] x2
  int tid = threadIdx.x, lane = tid & 63, wv = tid >> 6;
  int wr = (wv>>2)*64, wc = (wv&3)*64;
  size_t Rm = (size_t)blockIdx.x * 128;
  const short* Ab = Hh + Rm*1024;
  f32x4 acc[4][4] = {};
  auto stA = [&](int c, short* dst){
#pragma unroll
    for (int jj = 0; jj < 2; ++jj){ int j = wv*2 + jj;
      gll16(Ab + (size_t)(j*8 + (lane>>3))*1024 + c*64 + (lane&7)*8, dst + j*512); }
  };
  auto stB = [&](int c, short* dst){
#pragma unroll
    for (int jj = 0; jj < 4; ++jj){ int j = wv*4 + jj;
      gll16(owB + (size_t)(j*8 + (lane>>3))*1024 + c*64 + (lane&7)*8, dst + j*512); }
  };
  stA(0, As); stB(0, Bs);
  __syncthreads();
  int buf = 0;
  for (int c = 0; c < 16; ++c){
    if (c+1 < 16){ stA(c+1, As + (buf^1)*8192); stB(c+1, Bs + (buf^1)*16384); }
    const short* At = As + buf*8192;
    const short* Bt = Bs + buf*16384;
#pragma unroll
    for (int kk = 0; kk < 2; ++kk){
      f16x8 av[4], bv[4];
#pragma unroll
      for (int mi = 0; mi < 4; ++mi) av[mi] = fragh(At, wr + mi*16, kk, lane);
#pragma unroll
      for (int ni = 0; ni < 4; ++ni) bv[ni] = fragh(Bt, wc + ni*16, kk, lane);
#pragma unroll
      for (int mi = 0; mi < 4; ++mi)
#pragma unroll
      for (int ni = 0; ni < 4; ++ni) acc[mi][ni] = MFMA16(av[mi], bv[ni], acc[mi][ni]);
    }
    __syncthreads();
    buf ^= 1;
  }
#pragma unroll
  for (int ni = 0; ni < 4; ++ni){
    int col = wc + ni*16 + (lane & 15);
    float bv = out_b[col];
#pragma unroll
    for (int mi = 0; mi < 4; ++mi)
#pragma unroll
    for (int r = 0; r < 4; ++r){
      size_t m = Rm + wr + mi*16 + ((lane>>4)<<2) + r;
      int t = (int)(m >> 8), bb = (int)(m & 255);
      out[(size_t)bb*32768 + (size_t)t*256 + col] = acc[mi][ni][r] + bv;
    }
  }
}

extern "C" void kernel_launch(void* const* d_in, const int* in_sizes, int n_in,
                              void* d_out, int out_size, void* d_ws, size_t ws_size,
                              hipStream_t stream) {
  (void)in_sizes; (void)n_in; (void)out_size; (void)ws_size;
  const float* latent = (const float*)d_in[0];
  const float* fc_W   = (const float*)d_in[1];
  const float* fc_b   = (const float*)d_in[2];
  const float* W_ih   = (const float*)d_in[3];
  const float* W_hh   = (const float*)d_in[4];
  const float* b_ih   = (const float*)d_in[5];
  const float* b_hh   = (const float*)d_in[6];
  const float* out_W  = (const float*)d_in[7];
  const float* out_b  = (const float*)d_in[8];
  float* out = (float*)d_out;
  char*  ws  = (char*)d_ws;
  const size_t MB = 1u << 20;
  short* WtF   = (short*)(ws + 0);               //  8 MB W_total fp16 frag blocks
  short* W0F   = (short*)(ws + 8*MB);            //  8 MB W_hh   fp16 frag blocks
  short* A0    = (short*)(ws + 16*MB);           // 512 KB h fp16 [256][1024] swz
  short* A1    = (short*)(ws + 16*MB + 524288);  // 512 KB
  float* bias0 = (float*)(ws + 17*MB);           //  16 KB permuted
  float* bias1 = (float*)(ws + 17*MB + 65536);   //  16 KB permuted
  short* owB   = (short*)(ws + 17*MB + 131072);  // 512 KB out_W fp16 swz
  short* WihF  = (short*)(ws + 18*MB);           //   2 MB W_ih fp16 swz
  short* owT   = (short*)(ws + 20*MB);           // 512 KB out_W^T fp16 swz
  short* latF  = (short*)(ws + 20*MB + 524288);  // 256 KB latent fp16 swz
  short* fcwF  = (short*)(ws + 21*MB);           //   1 MB fc_W fp16 swz
  unsigned* flg= (unsigned*)(ws + 22*MB);        //  32 KB flags
  short* Hh    = (short*)(ws + 23*MB);           //  64 MB h history fp16 swz

  k_prep<<<1024, 256, 0, stream>>>(W_ih, out_W, latent, fc_W, W_hh, b_ih, b_hh,
                                   WihF, owT, owB, latF, fcwF, W0F, bias0, flg);
  k_bias1<<<16, 256, 0, stream>>>(W_ih, out_b, bias0, bias1);
  k_wtotal<<<dim3(64,16), 256, 0, stream>>>(WihF, owT, W_hh, WtF);
  k_h0<<<dim3(4,16), 256, 0, stream>>>(latF, fcwF, fc_b, A0);
  k_persist<<<256, 512, 0, stream>>>(WtF, W0F, bias0, bias1, A0, A1, Hh, flg);
  k_y<<<256, 512, 0, stream>>>(Hh, owB, out_b, out);
}

// Round 4
// 649.754 us; speedup vs baseline: 4.4941x; 2.1921x over previous
//
#include <hip/hip_runtime.h>

// Decoder: h0 = latent@fc_W^T + fc_b ; 128-step LSTM with folded feedback
// (x_t = y_{t-1} folded into W_total = W_hh + W_ih@out_W) ; Y = H_hist@out_W^T + out_b.
// All fp16. k_persist runs ALL 128 steps: 8 chains of 32 batch rows, 32 WGs/chain,
// weights resident in VGPRs, A staged to LDS per step, c-state in registers.
// Cross-WG h exchange uses explicit sc0+sc1 (device-coherence-point) loads/stores:
// NO fences, no L2 invalidates. Per-step sync = per-chain 32-flag line, polled with
// 8 dwordx4 sc0 sc1 loads in one vmcnt round.
// Row-major fp16 ws matrices are "swz": elem (row,k) stored at k ^ ((row&7)<<3).

typedef __attribute__((ext_vector_type(8))) _Float16 f16x8;
typedef __attribute__((ext_vector_type(4))) float f32x4;
typedef __attribute__((ext_vector_type(4))) unsigned u32x4;

#define MFMA16(a,b,c) __builtin_amdgcn_mfma_f32_16x16x32_f16(a,b,c,0,0,0)

__device__ __forceinline__ short f2h(float x){
  return __builtin_bit_cast(short, (_Float16)x);
}
__device__ __forceinline__ unsigned pack2h(float a, float b){
  unsigned short ua = __builtin_bit_cast(unsigned short, (_Float16)a);
  unsigned short ub = __builtin_bit_cast(unsigned short, (_Float16)b);
  return (unsigned)ua | ((unsigned)ub << 16);
}

__device__ __forceinline__ void gll16(const void* g, void* l){
  __builtin_amdgcn_global_load_lds((const __attribute__((address_space(1))) void*)g,
                                   (__attribute__((address_space(3))) void*)l, 16, 0, 0);
}

// stage a 64x64 fp16 tile (pre-swizzled global, row-major ld=ldk) into LDS (linear image)
__device__ __forceinline__ void stage_t(const short* gRC, int ldk, short* lds, int lane, int wv){
#pragma unroll
  for (int jj = 0; jj < 2; ++jj){
    int j = wv*2 + jj;
    const short* src = gRC + (size_t)(j*8 + (lane>>3))*ldk + ((lane&7)*8);
    gll16(src, lds + j*512);
  }
}

// MFMA A/B fragment from a 64x64 swizzled LDS tile image
__device__ __forceinline__ f16x8 fragh(const short* t, int r, int kk, int lane){
  int row = r + (lane & 15);
  int k0  = (kk<<5) + ((lane>>4)<<3);
  return *(const f16x8*)(t + row*64 + (k0 ^ ((row & 7)<<3)));
}

// generic 64x64-tile fp16 GEMM core, CH k-chunks of 64
template<int CH>
__device__ __forceinline__ void core_k(const short* Ag, const short* Bg, int ldk,
                                       short* As, short* Bs, f32x4 (&acc)[2][2],
                                       int lane, int wv, int wr, int wc){
  stage_t(Ag, ldk, As, lane, wv);
  stage_t(Bg, ldk, Bs, lane, wv);
  __syncthreads();
  int buf = 0;
  for (int c = 0; c < CH; ++c){
    if (c+1 < CH){
      stage_t(Ag + (c+1)*64, ldk, As + (buf^1)*4096, lane, wv);
      stage_t(Bg + (c+1)*64, ldk, Bs + (buf^1)*4096, lane, wv);
    }
    const short* At = As + buf*4096;
    const short* Bt = Bs + buf*4096;
#pragma unroll
    for (int kk = 0; kk < 2; ++kk){
      f16x8 a0 = fragh(At, wr,    kk, lane), a1 = fragh(At, wr+16, kk, lane);
      f16x8 b0 = fragh(Bt, wc,    kk, lane), b1 = fragh(Bt, wc+16, kk, lane);
      acc[0][0] = MFMA16(a0,b0,acc[0][0]); acc[0][1] = MFMA16(a0,b1,acc[0][1]);
      acc[1][0] = MFMA16(a1,b0,acc[1][0]); acc[1][1] = MFMA16(a1,b1,acc[1][1]);
    }
    __syncthreads();
    buf ^= 1;
  }
}

// ---------------- setup ----------------
// Weight frag-block layout: block(c,s) = 512 shorts at ((c*32)+s)*512 ; within:
// lane l covers (gatecol p = 16c + (l&15), k = 32s + (l>>4)*8 .. +8). p is the
// PERMUTED gate index p = ((r&1023)<<2) | (r>>10) (unit*4+gate, torch i,f,g,o).

__global__ void k_prep(const float* __restrict__ W_ih, const float* __restrict__ out_W,
                       const float* __restrict__ latent, const float* __restrict__ fc_W,
                       const float* __restrict__ W_hh,
                       const float* __restrict__ b_ih, const float* __restrict__ b_hh,
                       short* __restrict__ WihF, short* __restrict__ owT,
                       short* __restrict__ owB, short* __restrict__ latF,
                       short* __restrict__ fcwF, short* __restrict__ W0F,
                       float* __restrict__ bias0, unsigned* __restrict__ flags){
  int T = blockDim.x*gridDim.x, t0 = blockIdx.x*blockDim.x + threadIdx.x;
  for (int i = t0; i < 8192; i += T) flags[i] = 0u;
  for (int idx = t0; idx < 4096*256; idx += T){    // WihF [4096][256] swz
    int r = idx >> 8, j = idx & 255;
    WihF[(size_t)r*256 + (j ^ ((r&7)<<3))] = f2h(W_ih[idx]);
  }
  for (int idx = t0; idx < 1024*256; idx += T){    // owT [1024][256]: owT[c][j]=out_W[j][c]
    int c = idx >> 8, j = idx & 255;
    owT[(size_t)c*256 + (j ^ ((c&7)<<3))] = f2h(out_W[(size_t)j*1024 + c]);
  }
  for (int idx = t0; idx < 256*1024; idx += T){    // owB [256][1024] swz
    int o = idx >> 10, k = idx & 1023;
    owB[(size_t)o*1024 + (k ^ ((o&7)<<3))] = f2h(out_W[idx]);
  }
  for (int idx = t0; idx < 256*512; idx += T){     // latF [256][512] swz
    int b = idx >> 9, j = idx & 511;
    latF[(size_t)b*512 + (j ^ ((b&7)<<3))] = f2h(latent[idx]);
  }
  for (int idx = t0; idx < 1024*512; idx += T){    // fcwF [1024][512] swz
    int n = idx >> 9, j = idx & 511;
    fcwF[(size_t)n*512 + (j ^ ((n&7)<<3))] = f2h(fc_W[idx]);
  }
  for (int idx = t0; idx < 4096*1024; idx += T){   // W0F = fp16(W_hh) frag blocks
    int r = idx >> 10, k = idx & 1023;
    int p = ((r & 1023)<<2) | (r >> 10);
    size_t a = ((size_t)(p>>4)*32 + (k>>5))*512 + ((size_t)((((k>>3)&3)<<4)|(p&15)))*8 + (k&7);
    W0F[a] = f2h(W_hh[idx]);
  }
  for (int r = t0; r < 4096; r += T){
    int rp = ((r & 1023)<<2) | (r >> 10);
    bias0[rp] = b_ih[r] + b_hh[r];
  }
}

__global__ void k_bias1(const float* __restrict__ W_ih, const float* __restrict__ out_b,
                        const float* __restrict__ bias0, float* __restrict__ bias1){
  int r = blockIdx.x*256 + threadIdx.x;            // 4096 threads
  float s = 0.f;
  for (int j = 0; j < 256; ++j) s += W_ih[(size_t)r*256 + j]*out_b[j];
  int rp = ((r & 1023)<<2) | (r >> 10);
  bias1[rp] = bias0[rp] + s;
}

// WtF = fp16(W_hh + W_ih@out_W), frag-block layout
__global__ __launch_bounds__(256) void k_wtotal(const short* __restrict__ WihF,
                                                const short* __restrict__ owT,
                                                const float* __restrict__ W_hh,
                                                short* __restrict__ WtF){
  __shared__ __align__(16) short As[2*4096];
  __shared__ __align__(16) short Bs[2*4096];
  int tid = threadIdx.x, lane = tid & 63, wv = tid >> 6;
  int wr = (wv>>1)*32, wc = (wv&1)*32;
  int Rm = blockIdx.x*64, Rn = blockIdx.y*64;
  f32x4 acc[2][2] = {};
  core_k<4>(WihF + (size_t)Rm*256, owT + (size_t)Rn*256, 256, As, Bs, acc, lane, wv, wr, wc);
#pragma unroll
  for (int mi = 0; mi < 2; ++mi)
#pragma unroll
  for (int ni = 0; ni < 2; ++ni)
#pragma unroll
  for (int r = 0; r < 4; ++r){
    int row = Rm + wr + mi*16 + ((lane>>4)<<2) + r;   // gate row
    int col = Rn + wc + ni*16 + (lane & 15);          // k
    float v = acc[mi][ni][r] + W_hh[(size_t)row*1024 + col];
    int p = ((row & 1023)<<2) | (row >> 10);
    size_t a = ((size_t)(p>>4)*32 + (col>>5))*512 + ((size_t)((((col>>3)&3)<<4)|(p&15)))*8 + (col&7);
    WtF[a] = f2h(v);
  }
}

// h0 = latent@fc_W^T + fc_b -> A0 fp16 swz
__global__ __launch_bounds__(256) void k_h0(const short* __restrict__ latF,
                                            const short* __restrict__ fcwF,
                                            const float* __restrict__ fc_b,
                                            short* __restrict__ A0){
  __shared__ __align__(16) short As[2*4096];
  __shared__ __align__(16) short Bs[2*4096];
  int tid = threadIdx.x, lane = tid & 63, wv = tid >> 6;
  int wr = (wv>>1)*32, wc = (wv&1)*32;
  int Rm = blockIdx.x*64, Rn = blockIdx.y*64;
  f32x4 acc[2][2] = {};
  core_k<8>(latF + (size_t)Rm*512, fcwF + (size_t)Rn*512, 512, As, Bs, acc, lane, wv, wr, wc);
#pragma unroll
  for (int mi = 0; mi < 2; ++mi)
#pragma unroll
  for (int ni = 0; ni < 2; ++ni)
#pragma unroll
  for (int r = 0; r < 4; ++r){
    int row = Rm + wr + mi*16 + ((lane>>4)<<2) + r;   // batch
    int col = Rn + wc + ni*16 + (lane & 15);          // unit
    float h = acc[mi][ni][r] + fc_b[col];
    A0[(size_t)row*1024 + (col ^ ((row&7)<<3))] = f2h(h);
  }
}

// ---------------- persistent kernel: steps 0..127 ----------------
// 256 WGs x 512 thr. chain = wg&7 (XCD-local under round-robin; correctness does
// NOT depend on it: all h exchange goes through sc0+sc1 at the device coherence
// point). WG: batch rows chain*32..+32, permuted gate cols gw*128..+128.
// Wave (wn=wv&3, kh=wv>>2): cols wn*32..+32 of WG block, k-half kh*512.
__global__ __launch_bounds__(512, 2) void k_persist(
    const short* __restrict__ WtF, const short* __restrict__ W0F,
    const float* __restrict__ bias0, const float* __restrict__ bias1,
    short* __restrict__ A0, short* __restrict__ A1, short* __restrict__ Hh,
    unsigned* __restrict__ flags){
  __shared__ __align__(16) short Asl[32*1024];      // 64 KB chain A slice (swz image)
  __shared__ __align__(16) float Lg0[32*132];       // kh=0 partial gates
  __shared__ __align__(16) float Lg1[32*132];       // kh=1 partial gates
  const int tid = threadIdx.x, lane = tid & 63, wv = tid >> 6;
  const int wg = blockIdx.x;
  const int chain = wg & 7, gw = wg >> 3;
  const int wn = wv & 3, kh = wv >> 2;
  const int cbase = gw*8 + wn*2, sbase = kh*16;

  // resident W_total fragments (128 VGPRs)
  f16x8 Breg[2][16];
  {
    const short* src = WtF + ((size_t)cbase*32 + sbase)*512 + lane*8;
#pragma unroll
    for (int cf = 0; cf < 2; ++cf)
#pragma unroll
      for (int s = 0; s < 16; ++s)
        Breg[cf][s] = *(const f16x8*)(src + (size_t)(cf*32 + s)*512);
  }
  const short* W0base = W0F + ((size_t)cbase*32 + sbase)*512 + lane*8;

  // A-frag addressing
  const int r0 = lane & 15;
  const int kq = (lane>>4)<<3;
  const int sw = (r0 & 7) << 3;

  // cell phase: thread (er,up) owns row er, units 2up,2up+1 of this WG
  const int er = tid >> 4, up = tid & 15;
  const int grow = chain*32 + er;
  const int swE = (grow & 7) << 3;
  const int ugl = gw*32 + 2*up;                     // even global unit
  const int posE = ugl ^ swE;                       // pair stays adjacent, 4B aligned
  const f32x4 b0qA = *(const f32x4*)(bias0 + gw*128 + 8*up);
  const f32x4 b0qB = *(const f32x4*)(bias0 + gw*128 + 8*up + 4);
  const f32x4 b1qA = *(const f32x4*)(bias1 + gw*128 + 8*up);
  const f32x4 b1qB = *(const f32x4*)(bias1 + gw*128 + 8*up + 4);
  float cA = 0.f, cB = 0.f;

  unsigned* flagC = flags + (size_t)chain*64;       // this chain's 32-flag line (128B)

  for (int t = 0; t < 128; ++t){
    const short* Ain = (t & 1) ? A1 : A0;
    short* Aout = (t & 1) ? A0 : A1;

    // ---- stage chain A slice: 8 coherent dwordx4 loads/lane -> LDS ----
    {
      u32x4 stg[8];
      const short* base = Ain + (size_t)(chain*32)*1024;
#pragma unroll
      for (int q = 0; q < 8; ++q){
        int i = wv*8 + q;
        const short* src = base + (size_t)(i>>1)*1024 + (i&1)*512 + lane*8;
        asm volatile("global_load_dwordx4 %0, %1, off sc0 sc1"
                     : "=v"(stg[q]) : "v"(src));
      }
      asm volatile("s_waitcnt vmcnt(0)" ::: "memory");
#pragma unroll
      for (int q = 0; q < 8; ++q){
        int i = wv*8 + q;
        *(u32x4*)((char*)Asl + (size_t)i*1024 + (size_t)lane*16) = stg[q];
      }
    }
    __syncthreads();

    f32x4 acc[2][2] = {};
    const short* Ar0 = Asl + r0*1024;
    const short* Ar1 = Asl + (16 + r0)*1024;
    if (t == 0){
#pragma unroll
      for (int s = 0; s < 16; ++s){
        int k = (sbase + s)*32 + kq;
        f16x8 w0 = *(const f16x8*)(W0base + (size_t)(0*32 + s)*512);
        f16x8 w1 = *(const f16x8*)(W0base + (size_t)(1*32 + s)*512);
        f16x8 a0 = *(const f16x8*)(Ar0 + (k ^ sw));
        f16x8 a1 = *(const f16x8*)(Ar1 + (k ^ sw));
        acc[0][0] = MFMA16(a0, w0, acc[0][0]);
        acc[0][1] = MFMA16(a0, w1, acc[0][1]);
        acc[1][0] = MFMA16(a1, w0, acc[1][0]);
        acc[1][1] = MFMA16(a1, w1, acc[1][1]);
      }
    } else {
#pragma unroll
      for (int s = 0; s < 16; ++s){
        int k = (sbase + s)*32 + kq;
        f16x8 a0 = *(const f16x8*)(Ar0 + (k ^ sw));
        f16x8 a1 = *(const f16x8*)(Ar1 + (k ^ sw));
        acc[0][0] = MFMA16(a0, Breg[0][s], acc[0][0]);
        acc[0][1] = MFMA16(a0, Breg[1][s], acc[0][1]);
        acc[1][0] = MFMA16(a1, Breg[0][s], acc[1][0]);
        acc[1][1] = MFMA16(a1, Breg[1][s], acc[1][1]);
      }
    }
    // partial gates -> LDS
    float* Lg = kh ? Lg1 : Lg0;
#pragma unroll
    for (int rf = 0; rf < 2; ++rf)
#pragma unroll
    for (int cf = 0; cf < 2; ++cf)
#pragma unroll
    for (int j = 0; j < 4; ++j)
      Lg[(rf*16 + ((lane>>4)<<2) + j)*132 + wn*32 + cf*16 + r0] = acc[rf][cf][j];
    __syncthreads();
    // ---- LSTM cell (k-half reduction + bias + nonlinearities), c in regs ----
    {
      f32x4 gA = *(const f32x4*)(Lg0 + er*132 + 8*up);
      f32x4 gB = *(const f32x4*)(Lg0 + er*132 + 8*up + 4);
      f32x4 hA = *(const f32x4*)(Lg1 + er*132 + 8*up);
      f32x4 hB = *(const f32x4*)(Lg1 + er*132 + 8*up + 4);
      gA = gA + hA + (t ? b1qA : b0qA);
      gB = gB + hB + (t ? b1qB : b0qB);
      float I0 = 1.f/(1.f+__expf(-gA[0])), F0 = 1.f/(1.f+__expf(-gA[1]));
      float G0 = tanhf(gA[2]),             O0 = 1.f/(1.f+__expf(-gA[3]));
      float I1 = 1.f/(1.f+__expf(-gB[0])), F1 = 1.f/(1.f+__expf(-gB[1]));
      float G1 = tanhf(gB[2]),             O1 = 1.f/(1.f+__expf(-gB[3]));
      cA = F0*cA + I0*G0;  float h0v = O0*tanhf(cA);
      cB = F1*cB + I1*G1;  float h1v = O1*tanhf(cB);
      unsigned pk = pack2h(h0v, h1v);
      short* pa = Aout + (size_t)grow*1024 + posE;
      asm volatile("global_store_dword %0, %1, off sc0 sc1" :: "v"(pa), "v"(pk));
      *(unsigned*)(Hh + (size_t)t*262144 + (size_t)grow*1024 + posE) = pk;  // plain
      asm volatile("s_waitcnt vmcnt(0)" ::: "memory");   // own stores at coherence point
    }
    if (t < 127){
      __syncthreads();                                   // whole WG's h is out
      if (tid == 0){
        unsigned val = (unsigned)(t+1);
        unsigned* fp = flagC + gw;
        asm volatile("global_store_dword %0, %1, off sc0 sc1" :: "v"(fp), "v"(val) : "memory");
      }
      if (wv == 0){
        const unsigned* pp = flagC + (size_t)lane*4;     // lanes 0..7 cover 32 flags
        unsigned tgt = (unsigned)(t+1);
        while (true){
          u32x4 f;
          asm volatile("global_load_dwordx4 %0, %1, off sc0 sc1\n\ts_waitcnt vmcnt(0)"
                       : "=v"(f) : "v"(pp) : "memory");
          bool ok = (lane >= 8) || (f[0] >= tgt && f[1] >= tgt && f[2] >= tgt && f[3] >= tgt);
          if (__all(ok)) break;
        }
      }
      __syncthreads();
    }
  }
}

// ---------------- final Y GEMM ----------------
// out[b][t][o] = Hh[t*256+b] . owB[o] + out_b[o] ; tile 128x256, 8 waves
__global__ __launch_bounds__(512) void k_y(const short* __restrict__ Hh,
                                           const short* __restrict__ owB,
                                           const float* __restrict__ out_b,
                                           float* __restrict__ out){
  __shared__ __align__(16) short As[2*8192];    // [128][64] x2
  __shared__ __align__(16) short Bs[2*16384];   // [256][64] x2
  int tid = threadIdx.x, lane = tid & 63, wv = tid >> 6;
  int wr = (wv>>2)*64, wc = (wv&3)*64;
  size_t Rm = (size_t)blockIdx.x * 128;
  const short* Ab = Hh + Rm*1024;
  f32x4 acc[4][4] = {};
  auto stA = [&](int c, short* dst){
#pragma unroll
    for (int jj = 0; jj < 2; ++jj){ int j = wv*2 + jj;
      gll16(Ab + (size_t)(j*8 + (lane>>3))*1024 + c*64 + (lane&7)*8, dst + j*512); }
  };
  auto stB = [&](int c, short* dst){
#pragma unroll
    for (int jj = 0; jj < 4; ++jj){ int j = wv*4 + jj;
      gll16(owB + (size_t)(j*8 + (lane>>3))*1024 + c*64 + (lane&7)*8, dst + j*512); }
  };
  stA(0, As); stB(0, Bs);
  __syncthreads();
  int buf = 0;
  for (int c = 0; c < 16; ++c){
    if (c+1 < 16){ stA(c+1, As + (buf^1)*8192); stB(c+1, Bs + (buf^1)*16384); }
    const short* At = As + buf*8192;
    const short* Bt = Bs + buf*16384;
#pragma unroll
    for (int kk = 0; kk < 2; ++kk){
      f16x8 av[4], bv[4];
#pragma unroll
      for (int mi = 0; mi < 4; ++mi) av[mi] = fragh(At, wr + mi*16, kk, lane);
#pragma unroll
      for (int ni = 0; ni < 4; ++ni) bv[ni] = fragh(Bt, wc + ni*16, kk, lane);
#pragma unroll
      for (int mi = 0; mi < 4; ++mi)
#pragma unroll
      for (int ni = 0; ni < 4; ++ni) acc[mi][ni] = MFMA16(av[mi], bv[ni], acc[mi][ni]);
    }
    __syncthreads();
    buf ^= 1;
  }
#pragma unroll
  for (int ni = 0; ni < 4; ++ni){
    int col = wc + ni*16 + (lane & 15);
    float bv = out_b[col];
#pragma unroll
    for (int mi = 0; mi < 4; ++mi)
#pragma unroll
    for (int r = 0; r < 4; ++r){
      size_t m = Rm + wr + mi*16 + ((lane>>4)<<2) + r;
      int t = (int)(m >> 8), bb = (int)(m & 255);
      out[(size_t)bb*32768 + (size_t)t*256 + col] = acc[mi][ni][r] + bv;
    }
  }
}

extern "C" void kernel_launch(void* const* d_in, const int* in_sizes, int n_in,
                              void* d_out, int out_size, void* d_ws, size_t ws_size,
                              hipStream_t stream) {
  (void)in_sizes; (void)n_in; (void)out_size; (void)ws_size;
  const float* latent = (const float*)d_in[0];
  const float* fc_W   = (const float*)d_in[1];
  const float* fc_b   = (const float*)d_in[2];
  const float* W_ih   = (const float*)d_in[3];
  const float* W_hh   = (const float*)d_in[4];
  const float* b_ih   = (const float*)d_in[5];
  const float* b_hh   = (const float*)d_in[6];
  const float* out_W  = (const float*)d_in[7];
  const float* out_b  = (const float*)d_in[8];
  float* out = (float*)d_out;
  char*  ws  = (char*)d_ws;
  const size_t MB = 1u << 20;
  short* WtF   = (short*)(ws + 0);               //  8 MB W_total fp16 frag blocks
  short* W0F   = (short*)(ws + 8*MB);            //  8 MB W_hh   fp16 frag blocks
  short* A0    = (short*)(ws + 16*MB);           // 512 KB h fp16 [256][1024] swz
  short* A1    = (short*)(ws + 16*MB + 524288);  // 512 KB
  float* bias0 = (float*)(ws + 17*MB);           //  16 KB permuted
  float* bias1 = (float*)(ws + 17*MB + 65536);   //  16 KB permuted
  short* owB   = (short*)(ws + 17*MB + 131072);  // 512 KB out_W fp16 swz
  short* WihF  = (short*)(ws + 18*MB);           //   2 MB W_ih fp16 swz
  short* owT   = (short*)(ws + 20*MB);           // 512 KB out_W^T fp16 swz
  short* latF  = (short*)(ws + 20*MB + 524288);  // 256 KB latent fp16 swz
  short* fcwF  = (short*)(ws + 21*MB);           //   1 MB fc_W fp16 swz
  unsigned* flg= (unsigned*)(ws + 22*MB);        //  32 KB flags
  short* Hh    = (short*)(ws + 23*MB);           //  64 MB h history fp16 swz

  k_prep<<<1024, 256, 0, stream>>>(W_ih, out_W, latent, fc_W, W_hh, b_ih, b_hh,
                                   WihF, owT, owB, latF, fcwF, W0F, bias0, flg);
  k_bias1<<<16, 256, 0, stream>>>(W_ih, out_b, bias0, bias1);
  k_wtotal<<<dim3(64,16), 256, 0, stream>>>(WihF, owT, W_hh, WtF);
  k_h0<<<dim3(4,16), 256, 0, stream>>>(latF, fcwF, fc_b, A0);
  k_persist<<<256, 512, 0, stream>>>(WtF, W0F, bias0, bias1, A0, A1, Hh, flg);
  k_y<<<256, 512, 0, stream>>>(Hh, owB, out_b, out);
}